// Round 3
// baseline (297.420 us; speedup 1.0000x reference)
//
#include <hip/hip_runtime.h>

#define IN_F   360
#define HIDN   64
#define NCLS   5
#define BATCH  64
#define SEQ    128
#define NROWS  (BATCH*SEQ)   // 8192

// workspace layout (float offsets)
#define WS_FLAG  0            // int flag: 0 => scale==1 && trans==0 everywhere (fast path ok)
#define WS_WPACK 16           // float4[360*64] = 92160 floats (general path)
#define WS_WFAST 92176        // float2[360*64] = 46080 floats (fast path packed {C*ww, bw})
#define WS_WT4   138256       // 24576 floats (w_ih transposed, float4-packed)
#define WS_XEMB  162832       // 8192*64 = 524288
#define WS_GI    687120       // 8192*384 = 3145728
#define WS_HC    3832848      // 64*128 = 8192

#define LOG2E        1.4426950408889634f
#define NEG_HALF_L2E (-0.7213475204444817f)

__device__ __forceinline__ float fast_rcp(float x) { return __builtin_amdgcn_rcpf(x); }
__device__ __forceinline__ float fast_rsq(float x) { return __builtin_amdgcn_rsqf(x); }
__device__ __forceinline__ float sigmoid_(float x) {
    x = fminf(fmaxf(x, -60.0f), 60.0f);
    return fast_rcp(1.0f + exp2f(-LOG2E * x));
}
__device__ __forceinline__ float tanh_(float x) {
    x = fminf(fmaxf(x, -30.0f), 30.0f);
    float e = exp2f(-2.8853900817779268f * x);   // e^{-2x}
    return (1.0f - e) * fast_rcp(1.0f + e);
}

// ---------------- K0: weight prep + fast-path eligibility check ----------------
__global__ __launch_bounds__(256) void prep_kernel(
    const float* __restrict__ scale, const float* __restrict__ trans,
    const float* __restrict__ ww,    const float* __restrict__ bw,
    const float* __restrict__ wihf,  const float* __restrict__ wihb,
    float* __restrict__ ws) {
    int idx = blockIdx.x * 256 + threadIdx.x;
    float4* wpack  = (float4*)(ws + WS_WPACK);
    float2* wfast2 = (float2*)(ws + WS_WFAST);
    float*  wT4    = ws + WS_WT4;
    int*    flagp  = (int*)(ws + WS_FLAG);
    if (idx < 64 * IN_F) {
        int o = idx & 63, i = idx >> 6;
        float s  = scale[o * IN_F + i];
        float tr = trans[o * IN_F + i];
        if (s != 1.0f || tr != 0.0f) atomicOr(flagp, 1);
        float a  = 1.0f / s;
        float b  = -tr * a;
        float wq = 0.8673250705840776f * ww[o * IN_F + i];   // 2/(sqrt(3)*pi^0.25)
        float bb = bw[o * IN_F + i];
        wpack[i * 64 + o] = make_float4(a, b, wq, bb);
        wfast2[(i >> 1) * 128 + o * 2 + (i & 1)] = make_float2(wq, bb);
    }
    int idx2 = idx - 64 * IN_F;
    if (idx2 >= 0 && idx2 < 24576) {
        int e = idx2 & 3; int rest = idx2 >> 2;
        int g = rest % 384; int k4 = rest / 384;
        int k = k4 * 4 + e; int dir = g / 192; int gg = g - dir * 192;
        const float* src = dir ? wihb : wihf;
        wT4[idx2] = src[gg * 64 + k];
    }
}

// ---------------- K1: WavKAN + BatchNorm + LayerNorm ----------------
__global__ __launch_bounds__(256) void wavkan_kernel(
    const float* __restrict__ x_seq,
    const float* __restrict__ bn_g, const float* __restrict__ bn_b,
    const float* __restrict__ bn_m, const float* __restrict__ bn_v,
    const float* __restrict__ ln_g, const float* __restrict__ ln_b,
    const float* __restrict__ ws_c, float* __restrict__ x_emb) {
    __shared__ float2 xs_lds[16 * IN_F];   // 46 KB
    int t = threadIdx.x;
    int row0 = blockIdx.x * 16;
    int o = t & 63, grp = t >> 6;
    int fast = (*(const int*)(ws_c + WS_FLAG)) == 0;

    float acc0 = 0.f, acc1 = 0.f, acc2 = 0.f, acc3 = 0.f;

    if (fast) {
        for (int idx = t; idx < 16 * IN_F; idx += 256) {
            int r = idx / IN_F, i = idx - r * IN_F;
            float x = x_seq[(row0 + r) * IN_F + i];
            float u = x * x;
            float phi = (u - 1.0f) * exp2f(u * NEG_HALF_L2E);
            float sl  = x * fast_rcp(1.0f + exp2f(-LOG2E * x));
            xs_lds[idx] = make_float2(phi, sl);
        }
        __syncthreads();
        const float4* wf4 = (const float4*)(ws_c + WS_WFAST);
        const float4* xs4 = (const float4*)xs_lds;
        const float4* xr0 = xs4 + (grp * 4 + 0) * 180;
        const float4* xr1 = xs4 + (grp * 4 + 1) * 180;
        const float4* xr2 = xs4 + (grp * 4 + 2) * 180;
        const float4* xr3 = xs4 + (grp * 4 + 3) * 180;
        #pragma unroll 2
        for (int i2 = 0; i2 < 180; ++i2) {
            float4 wp = wf4[i2 * 64 + o];
            float4 a = xr0[i2];
            acc0 = fmaf(a.x, wp.x, acc0); acc0 = fmaf(a.y, wp.y, acc0);
            acc0 = fmaf(a.z, wp.z, acc0); acc0 = fmaf(a.w, wp.w, acc0);
            float4 b = xr1[i2];
            acc1 = fmaf(b.x, wp.x, acc1); acc1 = fmaf(b.y, wp.y, acc1);
            acc1 = fmaf(b.z, wp.z, acc1); acc1 = fmaf(b.w, wp.w, acc1);
            float4 c = xr2[i2];
            acc2 = fmaf(c.x, wp.x, acc2); acc2 = fmaf(c.y, wp.y, acc2);
            acc2 = fmaf(c.z, wp.z, acc2); acc2 = fmaf(c.w, wp.w, acc2);
            float4 d = xr3[i2];
            acc3 = fmaf(d.x, wp.x, acc3); acc3 = fmaf(d.y, wp.y, acc3);
            acc3 = fmaf(d.z, wp.z, acc3); acc3 = fmaf(d.w, wp.w, acc3);
        }
    } else {
        for (int idx = t; idx < 16 * IN_F; idx += 256) {
            int r = idx / IN_F, i = idx - r * IN_F;
            float x = x_seq[(row0 + r) * IN_F + i];
            float sl = x * fast_rcp(1.0f + exp2f(-LOG2E * x));
            xs_lds[idx] = make_float2(x, sl);
        }
        __syncthreads();
        const float4* wpack = (const float4*)(ws_c + WS_WPACK);
        const float2* xr0 = xs_lds + (grp * 4 + 0) * IN_F;
        const float2* xr1 = xs_lds + (grp * 4 + 1) * IN_F;
        const float2* xr2 = xs_lds + (grp * 4 + 2) * IN_F;
        const float2* xr3 = xs_lds + (grp * 4 + 3) * IN_F;
        for (int i = 0; i < IN_F; ++i) {
            float4 wp = wpack[i * 64 + o];
            {
                float2 xs = xr0[i];
                float xsc = fmaf(xs.x, wp.x, wp.y); float u = xsc * xsc;
                float e = exp2f(u * NEG_HALF_L2E);
                acc0 = fmaf((u - 1.0f) * e, wp.z, acc0);
                acc0 = fmaf(xs.y, wp.w, acc0);
            }
            {
                float2 xs = xr1[i];
                float xsc = fmaf(xs.x, wp.x, wp.y); float u = xsc * xsc;
                float e = exp2f(u * NEG_HALF_L2E);
                acc1 = fmaf((u - 1.0f) * e, wp.z, acc1);
                acc1 = fmaf(xs.y, wp.w, acc1);
            }
            {
                float2 xs = xr2[i];
                float xsc = fmaf(xs.x, wp.x, wp.y); float u = xsc * xsc;
                float e = exp2f(u * NEG_HALF_L2E);
                acc2 = fmaf((u - 1.0f) * e, wp.z, acc2);
                acc2 = fmaf(xs.y, wp.w, acc2);
            }
            {
                float2 xs = xr3[i];
                float xsc = fmaf(xs.x, wp.x, wp.y); float u = xsc * xsc;
                float e = exp2f(u * NEG_HALF_L2E);
                acc3 = fmaf((u - 1.0f) * e, wp.z, acc3);
                acc3 = fmaf(xs.y, wp.w, acc3);
            }
        }
    }

    float bscale = bn_g[o] * fast_rsq(bn_v[o] + 1e-5f);
    float bshift = fmaf(-bn_m[o], bscale, bn_b[o]);
    float lg = ln_g[o], lb = ln_b[o];
    float vals[4] = {acc0, acc1, acc2, acc3};
    #pragma unroll
    for (int rr = 0; rr < 4; ++rr) {
        float y = fmaf(vals[rr], bscale, bshift);
        float s = y;
        #pragma unroll
        for (int m = 1; m < 64; m <<= 1) s += __shfl_xor(s, m, 64);
        float mu = s * (1.0f / 64.0f);
        float d = y - mu;
        float s2 = d * d;
        #pragma unroll
        for (int m = 1; m < 64; m <<= 1) s2 += __shfl_xor(s2, m, 64);
        float rstd = fast_rsq(s2 * (1.0f / 64.0f) + 1e-5f);
        x_emb[(row0 + grp * 4 + rr) * 64 + o] = fmaf(d * rstd, lg, lb);
    }
}

// ---------------- K2: gi = x_emb @ w_ih^T + b_ih ----------------
// 256 blocks x 384 thr (thread = gate g). 32 rows/block staged in LDS;
// w_ih in registers amortized over 32 rows; broadcast ds reads are conflict-free.
__global__ __launch_bounds__(384) void gi_kernel(
    const float* __restrict__ ws_c,
    const float* __restrict__ bihf, const float* __restrict__ bihb,
    float* __restrict__ gi) {
    __shared__ __align__(16) float xs[32 * 64];   // 8 KB
    const float4* wT4   = (const float4*)(ws_c + WS_WT4);
    const float*  x_emb = ws_c + WS_XEMB;
    int t = threadIdx.x;
    int row0 = blockIdx.x * 32;
    {
        const float4* src = (const float4*)(x_emb + row0 * 64);
        float4* dst = (float4*)xs;
        for (int i = t; i < 512; i += 384) dst[i] = src[i];
    }
    int dir = t / 192, gg = t - dir * 192;
    float bih = dir ? bihb[gg] : bihf[gg];
    float4 w[16];
    #pragma unroll
    for (int k4 = 0; k4 < 16; ++k4) w[k4] = wT4[k4 * 384 + t];
    __syncthreads();
    for (int r = 0; r < 32; r += 2) {
        const float4* x0 = (const float4*)(xs + r * 64);
        const float4* x1 = (const float4*)(xs + r * 64 + 64);
        float a0 = bih, a1 = 0.f, b0 = bih, b1 = 0.f;
        #pragma unroll
        for (int k4 = 0; k4 < 16; k4 += 2) {
            float4 xv = x0[k4];     float4 wv = w[k4];
            a0 = fmaf(xv.x, wv.x, a0); a0 = fmaf(xv.y, wv.y, a0);
            a0 = fmaf(xv.z, wv.z, a0); a0 = fmaf(xv.w, wv.w, a0);
            float4 xu = x0[k4 + 1]; float4 wu = w[k4 + 1];
            a1 = fmaf(xu.x, wu.x, a1); a1 = fmaf(xu.y, wu.y, a1);
            a1 = fmaf(xu.z, wu.z, a1); a1 = fmaf(xu.w, wu.w, a1);
            float4 yv = x1[k4];
            b0 = fmaf(yv.x, wv.x, b0); b0 = fmaf(yv.y, wv.y, b0);
            b0 = fmaf(yv.z, wv.z, b0); b0 = fmaf(yv.w, wv.w, b0);
            float4 yu = x1[k4 + 1];
            b1 = fmaf(yu.x, wu.x, b1); b1 = fmaf(yu.y, wu.y, b1);
            b1 = fmaf(yu.z, wu.z, b1); b1 = fmaf(yu.w, wu.w, b1);
        }
        gi[(row0 + r) * 384 + t]     = a0 + a1;
        gi[(row0 + r + 1) * 384 + t] = b0 + b1;
    }
}

// ---------------- K3: bidirectional GRU — one wave per (b,dir), NO barriers ----------------
// lane = hidden unit j; W_hh rows (3 gates) in 192 VGPRs; h broadcast via readlane;
// gi prefetched 2 steps ahead — stays in flight (no vmcnt(0) barrier drain).
__global__ __launch_bounds__(64, 1) void gru_kernel(
    const float* __restrict__ ws_c,
    const float* __restrict__ whhf, const float* __restrict__ bhhf,
    const float* __restrict__ whhb, const float* __restrict__ bhhb,
    float* __restrict__ hc) {
    const float* gi = ws_c + WS_GI;
    int lane = threadIdx.x;
    int b = blockIdx.x & 63, dir = blockIdx.x >> 6;
    const float* whh = dir ? whhb : whhf;
    const float* bhh = dir ? bhhb : bhhf;

    float wr[64], wz[64], wn[64];
    {
        const float4* pr = (const float4*)(whh + lane * 64);
        const float4* pz = (const float4*)(whh + (64 + lane) * 64);
        const float4* pn = (const float4*)(whh + (128 + lane) * 64);
        #pragma unroll
        for (int q = 0; q < 16; ++q) {
            float4 a = pr[q];
            wr[4*q] = a.x; wr[4*q+1] = a.y; wr[4*q+2] = a.z; wr[4*q+3] = a.w;
            float4 c = pz[q];
            wz[4*q] = c.x; wz[4*q+1] = c.y; wz[4*q+2] = c.z; wz[4*q+3] = c.w;
            float4 d = pn[q];
            wn[4*q] = d.x; wn[4*q+1] = d.y; wn[4*q+2] = d.z; wn[4*q+3] = d.w;
        }
    }
    float br = bhh[lane], bz = bhh[64 + lane], bnn = bhh[128 + lane];
    float hreg = 0.0f;
    int step = dir ? -1 : 1;
    int s0 = dir ? (SEQ - 1) : 0;
    const float* gbase = gi + (b * SEQ) * 384 + dir * 192 + lane;

    float ir  = gbase[s0 * 384],          iz  = gbase[s0 * 384 + 64],          inn = gbase[s0 * 384 + 128];
    float ir1 = gbase[(s0 + step) * 384], iz1 = gbase[(s0 + step) * 384 + 64], in1 = gbase[(s0 + step) * 384 + 128];

    for (int ss = 0; ss < SEQ; ++ss) {
        float nir = 0.f, niz = 0.f, nin = 0.f;
        if (ss < SEQ - 2) {
            int ai = (s0 + (ss + 2) * step) * 384;
            nir = gbase[ai]; niz = gbase[ai + 64]; nin = gbase[ai + 128];
        }
        float ar0 = ir + br, ar1 = 0.f, ar2 = 0.f, ar3 = 0.f;
        float az0 = iz + bz, az1 = 0.f, az2 = 0.f, az3 = 0.f;
        float an0 = bnn,     an1 = 0.f, an2 = 0.f, an3 = 0.f;
        #pragma unroll
        for (int k = 0; k < 64; k += 4) {
            float h0 = __shfl(hreg, k, 64);
            float h1 = __shfl(hreg, k + 1, 64);
            float h2 = __shfl(hreg, k + 2, 64);
            float h3 = __shfl(hreg, k + 3, 64);
            ar0 = fmaf(wr[k],     h0, ar0); az0 = fmaf(wz[k],     h0, az0); an0 = fmaf(wn[k],     h0, an0);
            ar1 = fmaf(wr[k + 1], h1, ar1); az1 = fmaf(wz[k + 1], h1, az1); an1 = fmaf(wn[k + 1], h1, an1);
            ar2 = fmaf(wr[k + 2], h2, ar2); az2 = fmaf(wz[k + 2], h2, az2); an2 = fmaf(wn[k + 2], h2, an2);
            ar3 = fmaf(wr[k + 3], h3, ar3); az3 = fmaf(wz[k + 3], h3, az3); an3 = fmaf(wn[k + 3], h3, an3);
        }
        float r = sigmoid_((ar0 + ar1) + (ar2 + ar3));
        float z = sigmoid_((az0 + az1) + (az2 + az3));
        float ghn = (an0 + an1) + (an2 + an3);
        float n = tanh_(fmaf(r, ghn, inn));
        hreg = fmaf(z, hreg - n, n);           // (1-z)*n + z*h
        ir = ir1; iz = iz1; inn = in1;
        ir1 = nir; iz1 = niz; in1 = nin;
    }
    hc[b * 128 + dir * 64 + lane] = hreg;
}

// ---------------- K4: classifier head ----------------
__global__ __launch_bounds__(64) void head_kernel(
    const float* __restrict__ ws_c,
    const float* __restrict__ fc1w, const float* __restrict__ fc1b,
    const float* __restrict__ fc2w, const float* __restrict__ fc2b,
    float* __restrict__ out) {
    __shared__ __align__(16) float hr[128];
    __shared__ float h1[64];
    const float* hc = ws_c + WS_HC;
    int bb = blockIdx.x, t = threadIdx.x;
    hr[t]      = hc[bb * 128 + t];
    hr[64 + t] = hc[bb * 128 + 64 + t];
    __syncthreads();
    float acc = fc1b[t];
    const float4* w4 = (const float4*)(fc1w + t * 128);
    const float4* h4 = (const float4*)hr;
    #pragma unroll 8
    for (int k4 = 0; k4 < 32; ++k4) {
        float4 wv = w4[k4]; float4 hv = h4[k4];
        acc = fmaf(hv.x, wv.x, acc); acc = fmaf(hv.y, wv.y, acc);
        acc = fmaf(hv.z, wv.z, acc); acc = fmaf(hv.w, wv.w, acc);
    }
    h1[t] = fmaxf(acc, 0.0f);
    __syncthreads();
    if (t < NCLS) {
        float acc2 = fc2b[t];
        const float* wr = fc2w + t * 64;
        #pragma unroll 8
        for (int k = 0; k < 64; ++k) acc2 = fmaf(h1[k], wr[k], acc2);
        out[bb * NCLS + t] = acc2;
    }
}

extern "C" void kernel_launch(void* const* d_in, const int* in_sizes, int n_in,
                              void* d_out, int out_size, void* d_ws, size_t ws_size,
                              hipStream_t stream) {
    const float* x_seq = (const float*)d_in[0];
    const float* wscal = (const float*)d_in[1];
    const float* wtran = (const float*)d_in[2];
    const float* wwght = (const float*)d_in[3];
    const float* bwght = (const float*)d_in[4];
    const float* bn_g  = (const float*)d_in[5];
    const float* bn_b  = (const float*)d_in[6];
    const float* bn_m  = (const float*)d_in[7];
    const float* bn_v  = (const float*)d_in[8];
    const float* ln_g  = (const float*)d_in[9];
    const float* ln_b  = (const float*)d_in[10];
    const float* wihf  = (const float*)d_in[11];
    const float* whhf  = (const float*)d_in[12];
    const float* bihf  = (const float*)d_in[13];
    const float* bhhf  = (const float*)d_in[14];
    const float* wihb  = (const float*)d_in[15];
    const float* whhb  = (const float*)d_in[16];
    const float* bihb  = (const float*)d_in[17];
    const float* bhhb  = (const float*)d_in[18];
    const float* fc1w  = (const float*)d_in[19];
    const float* fc1b  = (const float*)d_in[20];
    const float* fc2w  = (const float*)d_in[21];
    const float* fc2b  = (const float*)d_in[22];
    float* ws  = (float*)d_ws;
    float* out = (float*)d_out;

    hipMemsetAsync(ws + WS_FLAG, 0, sizeof(int), stream);
    hipLaunchKernelGGL(prep_kernel, dim3(186), dim3(256), 0, stream,
                       wscal, wtran, wwght, bwght, wihf, wihb, ws);
    hipLaunchKernelGGL(wavkan_kernel, dim3(NROWS / 16), dim3(256), 0, stream,
                       x_seq, bn_g, bn_b, bn_m, bn_v, ln_g, ln_b, ws, ws + WS_XEMB);
    hipLaunchKernelGGL(gi_kernel, dim3(NROWS / 32), dim3(384), 0, stream,
                       ws, bihf, bihb, ws + WS_GI);
    hipLaunchKernelGGL(gru_kernel, dim3(128), dim3(64), 0, stream,
                       ws, whhf, bhhf, whhb, bhhb, ws + WS_HC);
    hipLaunchKernelGGL(head_kernel, dim3(64), dim3(64), 0, stream,
                       ws, fc1w, fc1b, fc2w, fc2b, out);
}

// Round 5
// 239.731 us; speedup vs baseline: 1.2406x; 1.2406x over previous
//
#include <hip/hip_runtime.h>

#define IN_F   360
#define HIDN   64
#define NCLS   5
#define BATCH  64
#define SEQ    128
#define NROWS  (BATCH*SEQ)   // 8192

// workspace layout (float offsets)
#define WS_FLAG  0            // int flag: 0 => scale==1 && trans==0 everywhere (fast path ok)
#define WS_WPACK 16           // float4[360*64] = 92160 floats (general path)
#define WS_WFAST 92176        // float2[360*64] = 46080 floats (fast path packed {C*ww, bw})
#define WS_WT4   138256       // 24576 floats (w_ih transposed, float4-packed)
#define WS_XEMB  162832       // 8192*64 = 524288
#define WS_GI    687120       // 8192*384 = 3145728
#define WS_HC    3832848      // 64*128 = 8192

#define LOG2E        1.4426950408889634f
#define NEG_HALF_L2E (-0.7213475204444817f)

__device__ __forceinline__ float fast_rcp(float x) { return __builtin_amdgcn_rcpf(x); }
__device__ __forceinline__ float fast_rsq(float x) { return __builtin_amdgcn_rsqf(x); }
__device__ __forceinline__ float sigmoid_(float x) {
    x = fminf(fmaxf(x, -60.0f), 60.0f);
    return fast_rcp(1.0f + exp2f(-LOG2E * x));
}
__device__ __forceinline__ float tanh_(float x) {
    x = fminf(fmaxf(x, -30.0f), 30.0f);
    float e = exp2f(-2.8853900817779268f * x);   // e^{-2x}
    return (1.0f - e) * fast_rcp(1.0f + e);
}

// ---------------- K0: weight prep + fast-path eligibility check ----------------
__global__ __launch_bounds__(256) void prep_kernel(
    const float* __restrict__ scale, const float* __restrict__ trans,
    const float* __restrict__ ww,    const float* __restrict__ bw,
    const float* __restrict__ wihf,  const float* __restrict__ wihb,
    float* __restrict__ ws) {
    int idx = blockIdx.x * 256 + threadIdx.x;
    float4* wpack  = (float4*)(ws + WS_WPACK);
    float2* wfast2 = (float2*)(ws + WS_WFAST);
    float*  wT4    = ws + WS_WT4;
    int*    flagp  = (int*)(ws + WS_FLAG);
    if (idx < 64 * IN_F) {
        int o = idx & 63, i = idx >> 6;
        float s  = scale[o * IN_F + i];
        float tr = trans[o * IN_F + i];
        if (s != 1.0f || tr != 0.0f) atomicOr(flagp, 1);
        float a  = 1.0f / s;
        float b  = -tr * a;
        float wq = 0.8673250705840776f * ww[o * IN_F + i];   // 2/(sqrt(3)*pi^0.25)
        float bb = bw[o * IN_F + i];
        wpack[i * 64 + o] = make_float4(a, b, wq, bb);
        wfast2[(i >> 1) * 128 + o * 2 + (i & 1)] = make_float2(wq, bb);
    }
    int idx2 = idx - 64 * IN_F;
    if (idx2 >= 0 && idx2 < 24576) {
        int e = idx2 & 3; int rest = idx2 >> 2;
        int g = rest % 384; int k4 = rest / 384;
        int k = k4 * 4 + e; int dir = g / 192; int gg = g - dir * 192;
        const float* src = dir ? wihb : wihf;
        wT4[idx2] = src[gg * 64 + k];
    }
}

// ---------------- K1: WavKAN + BatchNorm + LayerNorm ----------------
__global__ __launch_bounds__(256) void wavkan_kernel(
    const float* __restrict__ x_seq,
    const float* __restrict__ bn_g, const float* __restrict__ bn_b,
    const float* __restrict__ bn_m, const float* __restrict__ bn_v,
    const float* __restrict__ ln_g, const float* __restrict__ ln_b,
    const float* __restrict__ ws_c, float* __restrict__ x_emb) {
    __shared__ float2 xs_lds[16 * IN_F];   // 46 KB
    int t = threadIdx.x;
    int row0 = blockIdx.x * 16;
    int o = t & 63, grp = t >> 6;
    int fast = (*(const int*)(ws_c + WS_FLAG)) == 0;

    float acc0 = 0.f, acc1 = 0.f, acc2 = 0.f, acc3 = 0.f;

    if (fast) {
        for (int idx = t; idx < 16 * IN_F; idx += 256) {
            int r = idx / IN_F, i = idx - r * IN_F;
            float x = x_seq[(row0 + r) * IN_F + i];
            float u = x * x;
            float phi = (u - 1.0f) * exp2f(u * NEG_HALF_L2E);
            float sl  = x * fast_rcp(1.0f + exp2f(-LOG2E * x));
            xs_lds[idx] = make_float2(phi, sl);
        }
        __syncthreads();
        const float4* wf4 = (const float4*)(ws_c + WS_WFAST);
        const float4* xs4 = (const float4*)xs_lds;
        const float4* xr0 = xs4 + (grp * 4 + 0) * 180;
        const float4* xr1 = xs4 + (grp * 4 + 1) * 180;
        const float4* xr2 = xs4 + (grp * 4 + 2) * 180;
        const float4* xr3 = xs4 + (grp * 4 + 3) * 180;
        #pragma unroll 2
        for (int i2 = 0; i2 < 180; ++i2) {
            float4 wp = wf4[i2 * 64 + o];
            float4 a = xr0[i2];
            acc0 = fmaf(a.x, wp.x, acc0); acc0 = fmaf(a.y, wp.y, acc0);
            acc0 = fmaf(a.z, wp.z, acc0); acc0 = fmaf(a.w, wp.w, acc0);
            float4 b = xr1[i2];
            acc1 = fmaf(b.x, wp.x, acc1); acc1 = fmaf(b.y, wp.y, acc1);
            acc1 = fmaf(b.z, wp.z, acc1); acc1 = fmaf(b.w, wp.w, acc1);
            float4 c = xr2[i2];
            acc2 = fmaf(c.x, wp.x, acc2); acc2 = fmaf(c.y, wp.y, acc2);
            acc2 = fmaf(c.z, wp.z, acc2); acc2 = fmaf(c.w, wp.w, acc2);
            float4 d = xr3[i2];
            acc3 = fmaf(d.x, wp.x, acc3); acc3 = fmaf(d.y, wp.y, acc3);
            acc3 = fmaf(d.z, wp.z, acc3); acc3 = fmaf(d.w, wp.w, acc3);
        }
    } else {
        for (int idx = t; idx < 16 * IN_F; idx += 256) {
            int r = idx / IN_F, i = idx - r * IN_F;
            float x = x_seq[(row0 + r) * IN_F + i];
            float sl = x * fast_rcp(1.0f + exp2f(-LOG2E * x));
            xs_lds[idx] = make_float2(x, sl);
        }
        __syncthreads();
        const float4* wpack = (const float4*)(ws_c + WS_WPACK);
        const float2* xr0 = xs_lds + (grp * 4 + 0) * IN_F;
        const float2* xr1 = xs_lds + (grp * 4 + 1) * IN_F;
        const float2* xr2 = xs_lds + (grp * 4 + 2) * IN_F;
        const float2* xr3 = xs_lds + (grp * 4 + 3) * IN_F;
        for (int i = 0; i < IN_F; ++i) {
            float4 wp = wpack[i * 64 + o];
            {
                float2 xs = xr0[i];
                float xsc = fmaf(xs.x, wp.x, wp.y); float u = xsc * xsc;
                float e = exp2f(u * NEG_HALF_L2E);
                acc0 = fmaf((u - 1.0f) * e, wp.z, acc0);
                acc0 = fmaf(xs.y, wp.w, acc0);
            }
            {
                float2 xs = xr1[i];
                float xsc = fmaf(xs.x, wp.x, wp.y); float u = xsc * xsc;
                float e = exp2f(u * NEG_HALF_L2E);
                acc1 = fmaf((u - 1.0f) * e, wp.z, acc1);
                acc1 = fmaf(xs.y, wp.w, acc1);
            }
            {
                float2 xs = xr2[i];
                float xsc = fmaf(xs.x, wp.x, wp.y); float u = xsc * xsc;
                float e = exp2f(u * NEG_HALF_L2E);
                acc2 = fmaf((u - 1.0f) * e, wp.z, acc2);
                acc2 = fmaf(xs.y, wp.w, acc2);
            }
            {
                float2 xs = xr3[i];
                float xsc = fmaf(xs.x, wp.x, wp.y); float u = xsc * xsc;
                float e = exp2f(u * NEG_HALF_L2E);
                acc3 = fmaf((u - 1.0f) * e, wp.z, acc3);
                acc3 = fmaf(xs.y, wp.w, acc3);
            }
        }
    }

    float bscale = bn_g[o] * fast_rsq(bn_v[o] + 1e-5f);
    float bshift = fmaf(-bn_m[o], bscale, bn_b[o]);
    float lg = ln_g[o], lb = ln_b[o];
    float vals[4] = {acc0, acc1, acc2, acc3};
    #pragma unroll
    for (int rr = 0; rr < 4; ++rr) {
        float y = fmaf(vals[rr], bscale, bshift);
        float s = y;
        #pragma unroll
        for (int m = 1; m < 64; m <<= 1) s += __shfl_xor(s, m, 64);
        float mu = s * (1.0f / 64.0f);
        float d = y - mu;
        float s2 = d * d;
        #pragma unroll
        for (int m = 1; m < 64; m <<= 1) s2 += __shfl_xor(s2, m, 64);
        float rstd = fast_rsq(s2 * (1.0f / 64.0f) + 1e-5f);
        x_emb[(row0 + grp * 4 + rr) * 64 + o] = fmaf(d * rstd, lg, lb);
    }
}

// ---------------- K2: gi = x_emb @ w_ih^T + b_ih ----------------
__global__ __launch_bounds__(384) void gi_kernel(
    const float* __restrict__ ws_c,
    const float* __restrict__ bihf, const float* __restrict__ bihb,
    float* __restrict__ gi) {
    __shared__ __align__(16) float xs[32 * 64];   // 8 KB
    const float4* wT4   = (const float4*)(ws_c + WS_WT4);
    const float*  x_emb = ws_c + WS_XEMB;
    int t = threadIdx.x;
    int row0 = blockIdx.x * 32;
    {
        const float4* src = (const float4*)(x_emb + row0 * 64);
        float4* dst = (float4*)xs;
        for (int i = t; i < 512; i += 384) dst[i] = src[i];
    }
    int dir = t / 192, gg = t - dir * 192;
    float bih = dir ? bihb[gg] : bihf[gg];
    float4 w[16];
    #pragma unroll
    for (int k4 = 0; k4 < 16; ++k4) w[k4] = wT4[k4 * 384 + t];
    __syncthreads();
    for (int r = 0; r < 32; r += 2) {
        const float4* x0 = (const float4*)(xs + r * 64);
        const float4* x1 = (const float4*)(xs + r * 64 + 64);
        float a0 = bih, a1 = 0.f, b0 = bih, b1 = 0.f;
        #pragma unroll
        for (int k4 = 0; k4 < 16; k4 += 2) {
            float4 xv = x0[k4];     float4 wv = w[k4];
            a0 = fmaf(xv.x, wv.x, a0); a0 = fmaf(xv.y, wv.y, a0);
            a0 = fmaf(xv.z, wv.z, a0); a0 = fmaf(xv.w, wv.w, a0);
            float4 xu = x0[k4 + 1]; float4 wu = w[k4 + 1];
            a1 = fmaf(xu.x, wu.x, a1); a1 = fmaf(xu.y, wu.y, a1);
            a1 = fmaf(xu.z, wu.z, a1); a1 = fmaf(xu.w, wu.w, a1);
            float4 yv = x1[k4];
            b0 = fmaf(yv.x, wv.x, b0); b0 = fmaf(yv.y, wv.y, b0);
            b0 = fmaf(yv.z, wv.z, b0); b0 = fmaf(yv.w, wv.w, b0);
            float4 yu = x1[k4 + 1];
            b1 = fmaf(yu.x, wu.x, b1); b1 = fmaf(yu.y, wu.y, b1);
            b1 = fmaf(yu.z, wu.z, b1); b1 = fmaf(yu.w, wu.w, b1);
        }
        gi[(row0 + r) * 384 + t]     = a0 + a1;
        gi[(row0 + r + 1) * 384 + t] = b0 + b1;
    }
}

// ---------------- K3: bidirectional GRU recurrence ----------------
// EXACT R2 dataflow (known-passing): 128 blocks = (b,dir); 192 threads = gate rows;
// w_hh row in float4 regs; per-wave h_lds copies; gh double-buffer; 1 barrier/step;
// gates read gi at consumer lane. ONLY change vs R2: gi comes from an LDS preload
// (steps 0..63 in LDS, 64..127 in 64 scalar VGPRs dumped at the phase boundary),
// so the per-step barrier drains LDS only — no global loads inside the loop.
__global__ __launch_bounds__(192, 1) void gru_kernel(
    const float* __restrict__ ws_c,
    const float* __restrict__ whhf, const float* __restrict__ bhhf,
    const float* __restrict__ whhb, const float* __restrict__ bhhb,
    float* __restrict__ hc) {
    __shared__ __align__(16) float gi_l[64 * 192];   // 48 KB, [step][gate-float]
    __shared__ __align__(16) float h_lds[3][64];
    __shared__ float gh[2][192];
    const float* gi = ws_c + WS_GI;
    int t = threadIdx.x, wave = t >> 6, lane = t & 63;
    int b = blockIdx.x & 63, dir = blockIdx.x >> 6;
    const float* whh = dir ? whhb : whhf;
    const float* bhh = dir ? bhhb : bhhf;

    float4 w[16];
    const float4* wrow = (const float4*)(whh + t * 64);
    #pragma unroll
    for (int q = 0; q < 16; ++q) w[q] = wrow[q];
    float bias = bhh[t];

    // gi preload: thread t owns gate-float column (dir*192 + t) of each step row.
    const float* gsrc = gi + (size_t)(b * SEQ) * 384 + dir * 192 + t;
    #pragma unroll
    for (int q = 0; q < 64; ++q) {
        int sidx = dir ? (SEQ - 1 - q) : q;
        gi_l[q * 192 + t] = gsrc[sidx * 384];
    }
    float pf[64];
    #pragma unroll
    for (int q = 0; q < 64; ++q) {
        int sidx = dir ? (SEQ - 1 - (64 + q)) : (64 + q);
        pf[q] = gsrc[sidx * 384];
    }
    h_lds[wave][lane] = 0.0f;
    float hreg = 0.0f;
    __syncthreads();

    for (int ss = 0; ss < SEQ; ++ss) {
        if (ss == 64) {
            __syncthreads();                       // phase-1 reads complete
            #pragma unroll
            for (int q = 0; q < 64; ++q) gi_l[q * 192 + t] = pf[q];
            __syncthreads();                       // refill visible
        }
        int ssl = ss & 63;
        const float4* h4 = (const float4*)h_lds[wave];
        float a0 = bias, a1 = 0.f, a2 = 0.f, a3 = 0.f;
        #pragma unroll
        for (int q = 0; q < 16; ++q) {
            float4 hv = h4[q]; float4 wv = w[q];
            a0 = fmaf(hv.x, wv.x, a0); a1 = fmaf(hv.y, wv.y, a1);
            a2 = fmaf(hv.z, wv.z, a2); a3 = fmaf(hv.w, wv.w, a3);
        }
        int p = ss & 1;
        gh[p][t] = (a0 + a1) + (a2 + a3);
        __syncthreads();
        float ir  = gi_l[ssl * 192 + lane];
        float iz  = gi_l[ssl * 192 + 64 + lane];
        float in_ = gi_l[ssl * 192 + 128 + lane];
        float r = sigmoid_(ir + gh[p][lane]);
        float z = sigmoid_(iz + gh[p][64 + lane]);
        float n = tanh_(fmaf(r, gh[p][128 + lane], in_));
        hreg = fmaf(z, hreg - n, n);               // (1-z)*n + z*h, same in all waves
        h_lds[wave][lane] = hreg;                  // wave-private copy, DS in-order per wave
    }
    if (t < 64) hc[b * 128 + dir * 64 + lane] = hreg;
}

// ---------------- K4: classifier head ----------------
__global__ __launch_bounds__(64) void head_kernel(
    const float* __restrict__ ws_c,
    const float* __restrict__ fc1w, const float* __restrict__ fc1b,
    const float* __restrict__ fc2w, const float* __restrict__ fc2b,
    float* __restrict__ out) {
    __shared__ __align__(16) float hr[128];
    __shared__ float h1[64];
    const float* hc = ws_c + WS_HC;
    int bb = blockIdx.x, t = threadIdx.x;
    hr[t]      = hc[bb * 128 + t];
    hr[64 + t] = hc[bb * 128 + 64 + t];
    __syncthreads();
    float acc = fc1b[t];
    const float4* w4 = (const float4*)(fc1w + t * 128);
    const float4* h4 = (const float4*)hr;
    #pragma unroll 8
    for (int k4 = 0; k4 < 32; ++k4) {
        float4 wv = w4[k4]; float4 hv = h4[k4];
        acc = fmaf(hv.x, wv.x, acc); acc = fmaf(hv.y, wv.y, acc);
        acc = fmaf(hv.z, wv.z, acc); acc = fmaf(hv.w, wv.w, acc);
    }
    h1[t] = fmaxf(acc, 0.0f);
    __syncthreads();
    if (t < NCLS) {
        float acc2 = fc2b[t];
        const float* wr = fc2w + t * 64;
        #pragma unroll 8
        for (int k = 0; k < 64; ++k) acc2 = fmaf(h1[k], wr[k], acc2);
        out[bb * NCLS + t] = acc2;
    }
}

extern "C" void kernel_launch(void* const* d_in, const int* in_sizes, int n_in,
                              void* d_out, int out_size, void* d_ws, size_t ws_size,
                              hipStream_t stream) {
    const float* x_seq = (const float*)d_in[0];
    const float* wscal = (const float*)d_in[1];
    const float* wtran = (const float*)d_in[2];
    const float* wwght = (const float*)d_in[3];
    const float* bwght = (const float*)d_in[4];
    const float* bn_g  = (const float*)d_in[5];
    const float* bn_b  = (const float*)d_in[6];
    const float* bn_m  = (const float*)d_in[7];
    const float* bn_v  = (const float*)d_in[8];
    const float* ln_g  = (const float*)d_in[9];
    const float* ln_b  = (const float*)d_in[10];
    const float* wihf  = (const float*)d_in[11];
    const float* whhf  = (const float*)d_in[12];
    const float* bihf  = (const float*)d_in[13];
    const float* bhhf  = (const float*)d_in[14];
    const float* wihb  = (const float*)d_in[15];
    const float* whhb  = (const float*)d_in[16];
    const float* bihb  = (const float*)d_in[17];
    const float* bhhb  = (const float*)d_in[18];
    const float* fc1w  = (const float*)d_in[19];
    const float* fc1b  = (const float*)d_in[20];
    const float* fc2w  = (const float*)d_in[21];
    const float* fc2b  = (const float*)d_in[22];
    float* ws  = (float*)d_ws;
    float* out = (float*)d_out;

    hipMemsetAsync(ws + WS_FLAG, 0, sizeof(int), stream);
    hipLaunchKernelGGL(prep_kernel, dim3(186), dim3(256), 0, stream,
                       wscal, wtran, wwght, bwght, wihf, wihb, ws);
    hipLaunchKernelGGL(wavkan_kernel, dim3(NROWS / 16), dim3(256), 0, stream,
                       x_seq, bn_g, bn_b, bn_m, bn_v, ln_g, ln_b, ws, ws + WS_XEMB);
    hipLaunchKernelGGL(gi_kernel, dim3(NROWS / 32), dim3(384), 0, stream,
                       ws, bihf, bihb, ws + WS_GI);
    hipLaunchKernelGGL(gru_kernel, dim3(128), dim3(192), 0, stream,
                       ws, whhf, bhhf, whhb, bhhb, ws + WS_HC);
    hipLaunchKernelGGL(head_kernel, dim3(64), dim3(64), 0, stream,
                       ws, fc1w, fc1b, fc2w, fc2b, out);
}

// Round 7
// 222.637 us; speedup vs baseline: 1.3359x; 1.0768x over previous
//
#include <hip/hip_runtime.h>

#define IN_F   360
#define HIDN   64
#define NCLS   5
#define BATCH  64
#define SEQ    128
#define NROWS  (BATCH*SEQ)   // 8192

// workspace layout (float offsets)
#define WS_FLAG  0            // int flag: 0 => scale==1 && trans==0 everywhere (fast path ok)
#define WS_WPACK 16           // float4[360*64] = 92160 floats (general path)
#define WS_WFAST 92176        // float2[360*64] = 46080 floats (fast path packed {C*ww, bw})
#define WS_WT4   138256       // 24576 floats (w_ih transposed, float4-packed)
#define WS_XEMB  162832       // 8192*64 = 524288
#define WS_GI    687120       // 8192*384 = 3145728
#define WS_HC    3832848      // 64*128 = 8192

#define LOG2E        1.4426950408889634f
#define NEG_HALF_L2E (-0.7213475204444817f)

__device__ __forceinline__ float fast_rcp(float x) { return __builtin_amdgcn_rcpf(x); }
__device__ __forceinline__ float fast_rsq(float x) { return __builtin_amdgcn_rsqf(x); }
__device__ __forceinline__ float sigmoid_(float x) {
    x = fminf(fmaxf(x, -60.0f), 60.0f);
    return fast_rcp(1.0f + exp2f(-LOG2E * x));
}
__device__ __forceinline__ float tanh_(float x) {
    x = fminf(fmaxf(x, -30.0f), 30.0f);
    float e = exp2f(-2.8853900817779268f * x);   // e^{-2x}
    return (1.0f - e) * fast_rcp(1.0f + e);
}
// CRITICAL: __builtin_amdgcn_readlane is (int,int) — passing a float would
// NUMERICALLY convert (R4/R6 bug). Bit-cast in and out.
__device__ __forceinline__ float readlane_f(float v, int l) {
    return __int_as_float(__builtin_amdgcn_readlane(__float_as_int(v), l));
}

// ---------------- K0: weight prep + fast-path eligibility check ----------------
__global__ __launch_bounds__(256) void prep_kernel(
    const float* __restrict__ scale, const float* __restrict__ trans,
    const float* __restrict__ ww,    const float* __restrict__ bw,
    const float* __restrict__ wihf,  const float* __restrict__ wihb,
    float* __restrict__ ws) {
    int idx = blockIdx.x * 256 + threadIdx.x;
    float4* wpack  = (float4*)(ws + WS_WPACK);
    float2* wfast2 = (float2*)(ws + WS_WFAST);
    float*  wT4    = ws + WS_WT4;
    int*    flagp  = (int*)(ws + WS_FLAG);
    if (idx < 64 * IN_F) {
        int o = idx & 63, i = idx >> 6;
        float s  = scale[o * IN_F + i];
        float tr = trans[o * IN_F + i];
        if (s != 1.0f || tr != 0.0f) atomicOr(flagp, 1);
        float a  = 1.0f / s;
        float b  = -tr * a;
        float wq = 0.8673250705840776f * ww[o * IN_F + i];   // 2/(sqrt(3)*pi^0.25)
        float bb = bw[o * IN_F + i];
        wpack[i * 64 + o] = make_float4(a, b, wq, bb);
        wfast2[(i >> 1) * 128 + o * 2 + (i & 1)] = make_float2(wq, bb);
    }
    int idx2 = idx - 64 * IN_F;
    if (idx2 >= 0 && idx2 < 24576) {
        int e = idx2 & 3; int rest = idx2 >> 2;
        int g = rest % 384; int k4 = rest / 384;
        int k = k4 * 4 + e; int dir = g / 192; int gg = g - dir * 192;
        const float* src = dir ? wihb : wihf;
        wT4[idx2] = src[gg * 64 + k];
    }
}

// ---------------- K1: WavKAN + BatchNorm + LayerNorm ----------------
__global__ __launch_bounds__(256) void wavkan_kernel(
    const float* __restrict__ x_seq,
    const float* __restrict__ bn_g, const float* __restrict__ bn_b,
    const float* __restrict__ bn_m, const float* __restrict__ bn_v,
    const float* __restrict__ ln_g, const float* __restrict__ ln_b,
    const float* __restrict__ ws_c, float* __restrict__ x_emb) {
    __shared__ float2 xs_lds[16 * IN_F];   // 46 KB
    int t = threadIdx.x;
    int row0 = blockIdx.x * 16;
    int o = t & 63, grp = t >> 6;
    int fast = (*(const int*)(ws_c + WS_FLAG)) == 0;

    float acc0 = 0.f, acc1 = 0.f, acc2 = 0.f, acc3 = 0.f;

    if (fast) {
        for (int idx = t; idx < 16 * IN_F; idx += 256) {
            int r = idx / IN_F, i = idx - r * IN_F;
            float x = x_seq[(row0 + r) * IN_F + i];
            float u = x * x;
            float phi = (u - 1.0f) * exp2f(u * NEG_HALF_L2E);
            float sl  = x * fast_rcp(1.0f + exp2f(-LOG2E * x));
            xs_lds[idx] = make_float2(phi, sl);
        }
        __syncthreads();
        const float4* wf4 = (const float4*)(ws_c + WS_WFAST);
        const float4* xs4 = (const float4*)xs_lds;
        const float4* xr0 = xs4 + (grp * 4 + 0) * 180;
        const float4* xr1 = xs4 + (grp * 4 + 1) * 180;
        const float4* xr2 = xs4 + (grp * 4 + 2) * 180;
        const float4* xr3 = xs4 + (grp * 4 + 3) * 180;
        #pragma unroll 2
        for (int i2 = 0; i2 < 180; ++i2) {
            float4 wp = wf4[i2 * 64 + o];
            float4 a = xr0[i2];
            acc0 = fmaf(a.x, wp.x, acc0); acc0 = fmaf(a.y, wp.y, acc0);
            acc0 = fmaf(a.z, wp.z, acc0); acc0 = fmaf(a.w, wp.w, acc0);
            float4 b = xr1[i2];
            acc1 = fmaf(b.x, wp.x, acc1); acc1 = fmaf(b.y, wp.y, acc1);
            acc1 = fmaf(b.z, wp.z, acc1); acc1 = fmaf(b.w, wp.w, acc1);
            float4 c = xr2[i2];
            acc2 = fmaf(c.x, wp.x, acc2); acc2 = fmaf(c.y, wp.y, acc2);
            acc2 = fmaf(c.z, wp.z, acc2); acc2 = fmaf(c.w, wp.w, acc2);
            float4 d = xr3[i2];
            acc3 = fmaf(d.x, wp.x, acc3); acc3 = fmaf(d.y, wp.y, acc3);
            acc3 = fmaf(d.z, wp.z, acc3); acc3 = fmaf(d.w, wp.w, acc3);
        }
    } else {
        for (int idx = t; idx < 16 * IN_F; idx += 256) {
            int r = idx / IN_F, i = idx - r * IN_F;
            float x = x_seq[(row0 + r) * IN_F + i];
            float sl = x * fast_rcp(1.0f + exp2f(-LOG2E * x));
            xs_lds[idx] = make_float2(x, sl);
        }
        __syncthreads();
        const float4* wpack = (const float4*)(ws_c + WS_WPACK);
        const float2* xr0 = xs_lds + (grp * 4 + 0) * IN_F;
        const float2* xr1 = xs_lds + (grp * 4 + 1) * IN_F;
        const float2* xr2 = xs_lds + (grp * 4 + 2) * IN_F;
        const float2* xr3 = xs_lds + (grp * 4 + 3) * IN_F;
        for (int i = 0; i < IN_F; ++i) {
            float4 wp = wpack[i * 64 + o];
            {
                float2 xs = xr0[i];
                float xsc = fmaf(xs.x, wp.x, wp.y); float u = xsc * xsc;
                float e = exp2f(u * NEG_HALF_L2E);
                acc0 = fmaf((u - 1.0f) * e, wp.z, acc0);
                acc0 = fmaf(xs.y, wp.w, acc0);
            }
            {
                float2 xs = xr1[i];
                float xsc = fmaf(xs.x, wp.x, wp.y); float u = xsc * xsc;
                float e = exp2f(u * NEG_HALF_L2E);
                acc1 = fmaf((u - 1.0f) * e, wp.z, acc1);
                acc1 = fmaf(xs.y, wp.w, acc1);
            }
            {
                float2 xs = xr2[i];
                float xsc = fmaf(xs.x, wp.x, wp.y); float u = xsc * xsc;
                float e = exp2f(u * NEG_HALF_L2E);
                acc2 = fmaf((u - 1.0f) * e, wp.z, acc2);
                acc2 = fmaf(xs.y, wp.w, acc2);
            }
            {
                float2 xs = xr3[i];
                float xsc = fmaf(xs.x, wp.x, wp.y); float u = xsc * xsc;
                float e = exp2f(u * NEG_HALF_L2E);
                acc3 = fmaf((u - 1.0f) * e, wp.z, acc3);
                acc3 = fmaf(xs.y, wp.w, acc3);
            }
        }
    }

    float bscale = bn_g[o] * fast_rsq(bn_v[o] + 1e-5f);
    float bshift = fmaf(-bn_m[o], bscale, bn_b[o]);
    float lg = ln_g[o], lb = ln_b[o];
    float vals[4] = {acc0, acc1, acc2, acc3};
    #pragma unroll
    for (int rr = 0; rr < 4; ++rr) {
        float y = fmaf(vals[rr], bscale, bshift);
        float s = y;
        #pragma unroll
        for (int m = 1; m < 64; m <<= 1) s += __shfl_xor(s, m, 64);
        float mu = s * (1.0f / 64.0f);
        float d = y - mu;
        float s2 = d * d;
        #pragma unroll
        for (int m = 1; m < 64; m <<= 1) s2 += __shfl_xor(s2, m, 64);
        float rstd = fast_rsq(s2 * (1.0f / 64.0f) + 1e-5f);
        x_emb[(row0 + grp * 4 + rr) * 64 + o] = fmaf(d * rstd, lg, lb);
    }
}

// ---------------- K2: gi = x_emb @ w_ih^T + b_ih ----------------
__global__ __launch_bounds__(384) void gi_kernel(
    const float* __restrict__ ws_c,
    const float* __restrict__ bihf, const float* __restrict__ bihb,
    float* __restrict__ gi) {
    __shared__ __align__(16) float xs[32 * 64];   // 8 KB
    const float4* wT4   = (const float4*)(ws_c + WS_WT4);
    const float*  x_emb = ws_c + WS_XEMB;
    int t = threadIdx.x;
    int row0 = blockIdx.x * 32;
    {
        const float4* src = (const float4*)(x_emb + row0 * 64);
        float4* dst = (float4*)xs;
        for (int i = t; i < 512; i += 384) dst[i] = src[i];
    }
    int dir = t / 192, gg = t - dir * 192;
    float bih = dir ? bihb[gg] : bihf[gg];
    float4 w[16];
    #pragma unroll
    for (int k4 = 0; k4 < 16; ++k4) w[k4] = wT4[k4 * 384 + t];
    __syncthreads();
    for (int r = 0; r < 32; r += 2) {
        const float4* x0 = (const float4*)(xs + r * 64);
        const float4* x1 = (const float4*)(xs + r * 64 + 64);
        float a0 = bih, a1 = 0.f, b0 = bih, b1 = 0.f;
        #pragma unroll
        for (int k4 = 0; k4 < 16; k4 += 2) {
            float4 xv = x0[k4];     float4 wv = w[k4];
            a0 = fmaf(xv.x, wv.x, a0); a0 = fmaf(xv.y, wv.y, a0);
            a0 = fmaf(xv.z, wv.z, a0); a0 = fmaf(xv.w, wv.w, a0);
            float4 xu = x0[k4 + 1]; float4 wu = w[k4 + 1];
            a1 = fmaf(xu.x, wu.x, a1); a1 = fmaf(xu.y, wu.y, a1);
            a1 = fmaf(xu.z, wu.z, a1); a1 = fmaf(xu.w, wu.w, a1);
            float4 yv = x1[k4];
            b0 = fmaf(yv.x, wv.x, b0); b0 = fmaf(yv.y, wv.y, b0);
            b0 = fmaf(yv.z, wv.z, b0); b0 = fmaf(yv.w, wv.w, b0);
            float4 yu = x1[k4 + 1];
            b1 = fmaf(yu.x, wu.x, b1); b1 = fmaf(yu.y, wu.y, b1);
            b1 = fmaf(yu.z, wu.z, b1); b1 = fmaf(yu.w, wu.w, b1);
        }
        gi[(row0 + r) * 384 + t]     = a0 + a1;
        gi[(row0 + r + 1) * 384 + t] = b0 + b1;
    }
}

// ---------------- K3: bidirectional GRU recurrence ----------------
// R6 structure with the readlane type-coercion bug fixed via readlane_f
// (bit-cast). h broadcast from registers (hreg identical in all 3 waves);
// gi preload: steps 0..63 in LDS, 64..127 in 64 VGPRs dumped at phase boundary.
__global__ __launch_bounds__(192, 1) void gru_kernel(
    const float* __restrict__ ws_c,
    const float* __restrict__ whhf, const float* __restrict__ bhhf,
    const float* __restrict__ whhb, const float* __restrict__ bhhb,
    float* __restrict__ hc) {
    __shared__ __align__(16) float gi_l[64 * 192];   // 48 KB, [step][gate-float]
    __shared__ float gh[2][192];
    const float* gi = ws_c + WS_GI;
    int t = threadIdx.x, lane = t & 63;
    int b = blockIdx.x & 63, dir = blockIdx.x >> 6;
    const float* whh = dir ? whhb : whhf;
    const float* bhh = dir ? bhhb : bhhf;

    // thread t owns W_hh row t (gate = wave, unit = lane): 64 scalar VGPRs
    float w[64];
    {
        const float4* wrow = (const float4*)(whh + t * 64);
        #pragma unroll
        for (int q = 0; q < 16; ++q) {
            float4 a = wrow[q];
            w[4*q] = a.x; w[4*q+1] = a.y; w[4*q+2] = a.z; w[4*q+3] = a.w;
        }
    }
    float bias = bhh[t];

    // gi preload: thread t owns gate-float column (dir*192 + t) of each step row.
    const float* gsrc = gi + (size_t)(b * SEQ) * 384 + dir * 192 + t;
    #pragma unroll
    for (int q = 0; q < 64; ++q) {
        int sidx = dir ? (SEQ - 1 - q) : q;
        gi_l[q * 192 + t] = gsrc[sidx * 384];
    }
    float pf[64];
    #pragma unroll
    for (int q = 0; q < 64; ++q) {
        int sidx = dir ? (SEQ - 1 - (64 + q)) : (64 + q);
        pf[q] = gsrc[sidx * 384];
    }
    float hreg = 0.0f;
    __syncthreads();

    for (int ss = 0; ss < SEQ; ++ss) {
        if (ss == 64) {
            __syncthreads();                       // phase-1 reads complete
            #pragma unroll
            for (int q = 0; q < 64; ++q) gi_l[q * 192 + t] = pf[q];
            __syncthreads();                       // refill visible
        }
        int ssl = ss & 63;
        // matvec: own gate row x h, h broadcast from this wave's lane registers
        float a0 = bias, a1 = 0.f, a2 = 0.f, a3 = 0.f;
        #pragma unroll
        for (int k = 0; k < 64; k += 4) {
            float h0 = readlane_f(hreg, k);
            float h1 = readlane_f(hreg, k + 1);
            float h2 = readlane_f(hreg, k + 2);
            float h3 = readlane_f(hreg, k + 3);
            a0 = fmaf(w[k],     h0, a0);
            a1 = fmaf(w[k + 1], h1, a1);
            a2 = fmaf(w[k + 2], h2, a2);
            a3 = fmaf(w[k + 3], h3, a3);
        }
        int p = ss & 1;
        gh[p][t] = (a0 + a1) + (a2 + a3);
        // consumer-side gi reads (region only mutated across barrier-separated
        // phases, so reading before the barrier is safe; overlaps barrier wait)
        float ir  = gi_l[ssl * 192 + lane];
        float iz  = gi_l[ssl * 192 + 64 + lane];
        float in_ = gi_l[ssl * 192 + 128 + lane];
        __syncthreads();
        float r = sigmoid_(ir + gh[p][lane]);
        float z = sigmoid_(iz + gh[p][64 + lane]);
        float n = tanh_(fmaf(r, gh[p][128 + lane], in_));
        hreg = fmaf(z, hreg - n, n);               // (1-z)*n + z*h, same in all waves
    }
    if (t < 64) hc[b * 128 + dir * 64 + lane] = hreg;
}

// ---------------- K4: classifier head ----------------
__global__ __launch_bounds__(64) void head_kernel(
    const float* __restrict__ ws_c,
    const float* __restrict__ fc1w, const float* __restrict__ fc1b,
    const float* __restrict__ fc2w, const float* __restrict__ fc2b,
    float* __restrict__ out) {
    __shared__ __align__(16) float hr[128];
    __shared__ float h1[64];
    const float* hc = ws_c + WS_HC;
    int bb = blockIdx.x, t = threadIdx.x;
    hr[t]      = hc[bb * 128 + t];
    hr[64 + t] = hc[bb * 128 + 64 + t];
    __syncthreads();
    float acc = fc1b[t];
    const float4* w4 = (const float4*)(fc1w + t * 128);
    const float4* h4 = (const float4*)hr;
    #pragma unroll 8
    for (int k4 = 0; k4 < 32; ++k4) {
        float4 wv = w4[k4]; float4 hv = h4[k4];
        acc = fmaf(hv.x, wv.x, acc); acc = fmaf(hv.y, wv.y, acc);
        acc = fmaf(hv.z, wv.z, acc); acc = fmaf(hv.w, wv.w, acc);
    }
    h1[t] = fmaxf(acc, 0.0f);
    __syncthreads();
    if (t < NCLS) {
        float acc2 = fc2b[t];
        const float* wr = fc2w + t * 64;
        #pragma unroll 8
        for (int k = 0; k < 64; ++k) acc2 = fmaf(h1[k], wr[k], acc2);
        out[bb * NCLS + t] = acc2;
    }
}

extern "C" void kernel_launch(void* const* d_in, const int* in_sizes, int n_in,
                              void* d_out, int out_size, void* d_ws, size_t ws_size,
                              hipStream_t stream) {
    const float* x_seq = (const float*)d_in[0];
    const float* wscal = (const float*)d_in[1];
    const float* wtran = (const float*)d_in[2];
    const float* wwght = (const float*)d_in[3];
    const float* bwght = (const float*)d_in[4];
    const float* bn_g  = (const float*)d_in[5];
    const float* bn_b  = (const float*)d_in[6];
    const float* bn_m  = (const float*)d_in[7];
    const float* bn_v  = (const float*)d_in[8];
    const float* ln_g  = (const float*)d_in[9];
    const float* ln_b  = (const float*)d_in[10];
    const float* wihf  = (const float*)d_in[11];
    const float* whhf  = (const float*)d_in[12];
    const float* bihf  = (const float*)d_in[13];
    const float* bhhf  = (const float*)d_in[14];
    const float* wihb  = (const float*)d_in[15];
    const float* whhb  = (const float*)d_in[16];
    const float* bihb  = (const float*)d_in[17];
    const float* bhhb  = (const float*)d_in[18];
    const float* fc1w  = (const float*)d_in[19];
    const float* fc1b  = (const float*)d_in[20];
    const float* fc2w  = (const float*)d_in[21];
    const float* fc2b  = (const float*)d_in[22];
    float* ws  = (float*)d_ws;
    float* out = (float*)d_out;

    hipMemsetAsync(ws + WS_FLAG, 0, sizeof(int), stream);
    hipLaunchKernelGGL(prep_kernel, dim3(186), dim3(256), 0, stream,
                       wscal, wtran, wwght, bwght, wihf, wihb, ws);
    hipLaunchKernelGGL(wavkan_kernel, dim3(NROWS / 16), dim3(256), 0, stream,
                       x_seq, bn_g, bn_b, bn_m, bn_v, ln_g, ln_b, ws, ws + WS_XEMB);
    hipLaunchKernelGGL(gi_kernel, dim3(NROWS / 32), dim3(384), 0, stream,
                       ws, bihf, bihb, ws + WS_GI);
    hipLaunchKernelGGL(gru_kernel, dim3(128), dim3(192), 0, stream,
                       ws, whhf, bhhf, whhb, bhhb, ws + WS_HC);
    hipLaunchKernelGGL(head_kernel, dim3(64), dim3(64), 0, stream,
                       ws, fc1w, fc1b, fc2w, fc2b, out);
}